// Round 1
// baseline (177.746 us; speedup 1.0000x reference)
//
#include <hip/hip_runtime.h>
#include <math.h>

// -------- Kernel 1: per-(b,c) std (ddof=1) over H*W elements --------
// One block per (b,c) group. Vectorized float4 loads, wave+LDS reduction.
__global__ void bitsel_std_kernel(const float4* __restrict__ x,
                                  float* __restrict__ std_out,
                                  int n4 /* float4 count per (b,c) */) {
    const size_t base = (size_t)blockIdx.x * (size_t)n4;
    float sum = 0.f, sq = 0.f;
    for (int i = threadIdx.x; i < n4; i += blockDim.x) {
        float4 v = x[base + i];
        sum += (v.x + v.y) + (v.z + v.w);
        sq  += v.x * v.x + v.y * v.y + v.z * v.z + v.w * v.w;
    }
    // wave64 reduction
    for (int off = 32; off > 0; off >>= 1) {
        sum += __shfl_down(sum, off);
        sq  += __shfl_down(sq,  off);
    }
    __shared__ float s_sum[8], s_sq[8];
    const int wave = threadIdx.x >> 6;
    if ((threadIdx.x & 63) == 0) { s_sum[wave] = sum; s_sq[wave] = sq; }
    __syncthreads();
    if (threadIdx.x == 0) {
        float S = 0.f, Q = 0.f;
        const int nw = blockDim.x >> 6;
        for (int w = 0; w < nw; ++w) { S += s_sum[w]; Q += s_sq[w]; }
        const float N = (float)(n4 * 4);
        float var = (Q - S * S / N) / (N - 1.f);
        std_out[blockIdx.x] = sqrtf(fmaxf(var, 0.f));
    }
}

// -------- Kernel 2: head math (tiny). One block, threads 0..B-1 do batches,
// threads 0..2B-1 copy grad_feat passthrough. --------
__global__ void bitsel_head_kernel(const float* __restrict__ gf,
                                   const float* __restrict__ bits_in,
                                   const float* __restrict__ wbits_in,
                                   const float* __restrict__ Wl,
                                   const float* __restrict__ bl,
                                   const float* __restrict__ a1,
                                   const float* __restrict__ a2,
                                   const float* __restrict__ a3,
                                   const float* __restrict__ stds, // [B*C]
                                   float* __restrict__ out,        // full out buffer
                                   float* __restrict__ ws_a,
                                   float* __restrict__ ws_s,
                                   int B, int C, size_t Ntot /* residual elems */) {
    const int t = threadIdx.x;
    if (t < 2 * B) out[t] = gf[t];  // grad_feat passthrough
    if (t < B) {
        const int b = t;
        const int D = C + 2;
        float bt[3];
        for (int k = 0; k < 3; ++k) {
            float acc = gf[2 * b] * Wl[k * D] + gf[2 * b + 1] * Wl[k * D + 1];
            for (int c = 0; c < C; ++c) acc += stds[b * C + c] * Wl[k * D + 2 + c];
            bt[k] = acc + bl[k];
        }
        // argmax (first max wins, like jnp.argmax)
        int flag = 0; float m = bt[0];
        if (bt[1] > m) { m = bt[1]; flag = 1; }
        if (bt[2] > m) { m = bt[2]; flag = 2; }
        // softmax
        float e0 = expf(bt[0] - m), e1 = expf(bt[1] - m), e2 = expf(bt[2] - m);
        float esum = e0 + e1 + e2;
        float p1 = e0 / esum, p2 = e1 / esum, p3 = e2 / esum;
        float bits_hard = (flag == 0) ? 4.f : (flag == 1) ? 6.f : 8.f;
        float bits_soft = 4.f * p1 + 6.f * p2 + 8.f * p3;
        float bits_out  = (bits_hard - bits_soft) + bits_soft;  // STE forward
        float denom     = 4.f * p1 + 6.f * p2 + 8.f * p3;
        out[2 * B + Ntot + b]     = bits_in[b] + bits_out;
        out[2 * B + Ntot + B + b] = wbits_in[b] + bits_out / denom;
        // residual forward value == out_hard (+~1ulp) == fake_quant with flag's params
        float alpha = (flag == 0) ? a1[0] : (flag == 1) ? a2[0] : a3[0];
        float a = fabsf(alpha);
        float s = (exp2f(bits_hard - 1.f) - 1.f) / a; // (2^(k-1)-1)/|alpha|
        ws_a[b] = a;
        ws_s[b] = s;
    }
}

// -------- Kernel 3: elementwise fake-quant with per-batch (a, s) --------
__global__ void bitsel_quant_kernel(const float4* __restrict__ x,
                                    const float* __restrict__ ws_a,
                                    const float* __restrict__ ws_s,
                                    float4* __restrict__ res,
                                    int per_b4 /* float4 per batch */) {
    const int b = blockIdx.y;
    const float a = ws_a[b];
    const float s = ws_s[b];
    const size_t base = (size_t)b * (size_t)per_b4;
    const int stride = gridDim.x * blockDim.x;
    for (int i = blockIdx.x * blockDim.x + threadIdx.x; i < per_b4; i += stride) {
        float4 v = x[base + i];
        float4 r;
        r.x = rintf(fminf(fmaxf(v.x, -a), a) * s) / s;
        r.y = rintf(fminf(fmaxf(v.y, -a), a) * s) / s;
        r.z = rintf(fminf(fmaxf(v.z, -a), a) * s) / s;
        r.w = rintf(fminf(fmaxf(v.w, -a), a) * s) / s;
        res[base + i] = r;
    }
}

extern "C" void kernel_launch(void* const* d_in, const int* in_sizes, int n_in,
                              void* d_out, int out_size, void* d_ws, size_t ws_size,
                              hipStream_t stream) {
    const float* x     = (const float*)d_in[0];
    const float* gf    = (const float*)d_in[1];
    const float* bits  = (const float*)d_in[2];
    const float* wbits = (const float*)d_in[3];
    const float* Wl    = (const float*)d_in[4];
    const float* bl    = (const float*)d_in[5];
    const float* a1    = (const float*)d_in[6];
    const float* a2    = (const float*)d_in[7];
    const float* a3    = (const float*)d_in[8];
    float* out = (float*)d_out;

    const int B   = in_sizes[2];                 // 16
    const int C   = in_sizes[4] / 3 - 2;         // 64
    const int HWn = in_sizes[0] / (B * C);       // 65536
    const int BC  = B * C;                       // 1024
    const int n4  = HWn / 4;                     // 16384
    const int per_b4 = (C * HWn) / 4;            // 1048576
    const size_t Ntot = (size_t)in_sizes[0];     // residual element count

    float* ws_std = (float*)d_ws;   // BC floats
    float* ws_a   = ws_std + BC;    // B floats
    float* ws_s   = ws_a + B;       // B floats

    bitsel_std_kernel<<<BC, 256, 0, stream>>>((const float4*)x, ws_std, n4);

    bitsel_head_kernel<<<1, 64, 0, stream>>>(gf, bits, wbits, Wl, bl, a1, a2, a3,
                                             ws_std, out, ws_a, ws_s, B, C, Ntot);

    dim3 qgrid(256, B);
    bitsel_quant_kernel<<<qgrid, 256, 0, stream>>>((const float4*)x, ws_a, ws_s,
                                                   (float4*)(out + 2 * B), per_b4);
}

// Round 2
// 144.500 us; speedup vs baseline: 1.2301x; 1.2301x over previous
//
#include <hip/hip_runtime.h>
#include <math.h>

typedef float fx4 __attribute__((ext_vector_type(4)));

// -------- Kernel 1: per-(b,c) std (ddof=1) over H*W elements --------
// One block per (b,c) group. Vectorized float4 loads, wave+LDS reduction.
// Normal (caching) loads on purpose: this pass populates the 256 MiB L3
// with x so kernel 3 can re-read it from Infinity Cache.
__global__ void bitsel_std_kernel(const float4* __restrict__ x,
                                  float* __restrict__ std_out,
                                  int n4 /* float4 count per (b,c) */) {
    const size_t base = (size_t)blockIdx.x * (size_t)n4;
    float sum = 0.f, sq = 0.f;
    for (int i = threadIdx.x; i < n4; i += blockDim.x) {
        float4 v = x[base + i];
        sum += (v.x + v.y) + (v.z + v.w);
        sq  += v.x * v.x + v.y * v.y + v.z * v.z + v.w * v.w;
    }
    // wave64 reduction
    for (int off = 32; off > 0; off >>= 1) {
        sum += __shfl_down(sum, off);
        sq  += __shfl_down(sq,  off);
    }
    __shared__ float s_sum[8], s_sq[8];
    const int wave = threadIdx.x >> 6;
    if ((threadIdx.x & 63) == 0) { s_sum[wave] = sum; s_sq[wave] = sq; }
    __syncthreads();
    if (threadIdx.x == 0) {
        float S = 0.f, Q = 0.f;
        const int nw = blockDim.x >> 6;
        for (int w = 0; w < nw; ++w) { S += s_sum[w]; Q += s_sq[w]; }
        const float N = (float)(n4 * 4);
        float var = (Q - S * S / N) / (N - 1.f);
        std_out[blockIdx.x] = sqrtf(fmaxf(var, 0.f));
    }
}

// -------- Kernel 2: head math (tiny). One block. --------
__global__ void bitsel_head_kernel(const float* __restrict__ gf,
                                   const float* __restrict__ bits_in,
                                   const float* __restrict__ wbits_in,
                                   const float* __restrict__ Wl,
                                   const float* __restrict__ bl,
                                   const float* __restrict__ a1,
                                   const float* __restrict__ a2,
                                   const float* __restrict__ a3,
                                   const float* __restrict__ stds, // [B*C]
                                   float* __restrict__ out,        // full out buffer
                                   float* __restrict__ ws_a,
                                   float* __restrict__ ws_s,
                                   int B, int C, size_t Ntot /* residual elems */) {
    const int t = threadIdx.x;
    if (t < 2 * B) out[t] = gf[t];  // grad_feat passthrough
    if (t < B) {
        const int b = t;
        const int D = C + 2;
        float bt[3];
        for (int k = 0; k < 3; ++k) {
            float acc = gf[2 * b] * Wl[k * D] + gf[2 * b + 1] * Wl[k * D + 1];
            for (int c = 0; c < C; ++c) acc += stds[b * C + c] * Wl[k * D + 2 + c];
            bt[k] = acc + bl[k];
        }
        // argmax (first max wins, like jnp.argmax)
        int flag = 0; float m = bt[0];
        if (bt[1] > m) { m = bt[1]; flag = 1; }
        if (bt[2] > m) { m = bt[2]; flag = 2; }
        // softmax (max-subtracted, like jax.nn.softmax)
        float e0 = expf(bt[0] - m), e1 = expf(bt[1] - m), e2 = expf(bt[2] - m);
        float esum = e0 + e1 + e2;
        float p1 = e0 / esum, p2 = e1 / esum, p3 = e2 / esum;
        float bits_hard = (flag == 0) ? 4.f : (flag == 1) ? 6.f : 8.f;
        float bits_soft = 4.f * p1 + 6.f * p2 + 8.f * p3;
        float bits_out  = (bits_hard - bits_soft) + bits_soft;  // STE forward value
        float denom     = 4.f * p1 + 6.f * p2 + 8.f * p3;
        out[2 * B + Ntot + b]     = bits_in[b] + bits_out;
        out[2 * B + Ntot + B + b] = wbits_in[b] + bits_out / denom;
        // residual forward value == out_hard == fake_quant with flag's params
        float alpha = (flag == 0) ? a1[0] : (flag == 1) ? a2[0] : a3[0];
        float a = fabsf(alpha);
        float s = (exp2f(bits_hard - 1.f) - 1.f) / a; // (2^(k-1)-1)/|alpha|
        ws_a[b] = a;
        ws_s[b] = s;
    }
}

// -------- Kernel 3: elementwise fake-quant with per-batch (a, s) --------
// Chunks are processed in REVERSE address order (LRU-friendly: the x lines
// evicted by the residual write stream are the ones we read last), and the
// residual is written with non-temporal stores so it does not allocate in
// L2/L3 and evict the cached x.
__global__ void bitsel_quant_kernel(const fx4* __restrict__ x,
                                    const float* __restrict__ ws_a,
                                    const float* __restrict__ ws_s,
                                    fx4* __restrict__ res,
                                    int per_b4 /* float4 per batch */,
                                    int chunk4 /* float4 per chunk */,
                                    int nchunks) {
    const int g = nchunks - 1 - (int)blockIdx.x;   // reverse chunk order
    const size_t start = (size_t)g * (size_t)chunk4;
    const int b = (int)(start / (size_t)per_b4);
    const float a = ws_a[b];
    const float s = ws_s[b];
    for (int i = threadIdx.x; i < chunk4; i += blockDim.x) {
        fx4 v = x[start + i];
        fx4 r;
        r.x = rintf(fminf(fmaxf(v.x, -a), a) * s) / s;
        r.y = rintf(fminf(fmaxf(v.y, -a), a) * s) / s;
        r.z = rintf(fminf(fmaxf(v.z, -a), a) * s) / s;
        r.w = rintf(fminf(fmaxf(v.w, -a), a) * s) / s;
        __builtin_nontemporal_store(r, &res[start + i]);
    }
}

extern "C" void kernel_launch(void* const* d_in, const int* in_sizes, int n_in,
                              void* d_out, int out_size, void* d_ws, size_t ws_size,
                              hipStream_t stream) {
    const float* x     = (const float*)d_in[0];
    const float* gf    = (const float*)d_in[1];
    const float* bits  = (const float*)d_in[2];
    const float* wbits = (const float*)d_in[3];
    const float* Wl    = (const float*)d_in[4];
    const float* bl    = (const float*)d_in[5];
    const float* a1    = (const float*)d_in[6];
    const float* a2    = (const float*)d_in[7];
    const float* a3    = (const float*)d_in[8];
    float* out = (float*)d_out;

    const int B   = in_sizes[2];                 // 16
    const int C   = in_sizes[4] / 3 - 2;         // 64
    const int HWn = in_sizes[0] / (B * C);       // 65536
    const int BC  = B * C;                       // 1024
    const int n4  = HWn / 4;                     // 16384
    const int per_b4 = (C * HWn) / 4;            // 1048576 float4 per batch
    const size_t Ntot = (size_t)in_sizes[0];     // residual element count
    const int total4 = in_sizes[0] / 4;          // 16777216 float4 total
    const int chunk4 = 4096;                     // 64 KiB chunks (divides per_b4)
    const int nchunks = total4 / chunk4;         // 4096

    float* ws_std = (float*)d_ws;   // BC floats
    float* ws_a   = ws_std + BC;    // B floats
    float* ws_s   = ws_a + B;       // B floats

    bitsel_std_kernel<<<BC, 256, 0, stream>>>((const float4*)x, ws_std, n4);

    bitsel_head_kernel<<<1, 64, 0, stream>>>(gf, bits, wbits, Wl, bl, a1, a2, a3,
                                             ws_std, out, ws_a, ws_s, B, C, Ntot);

    bitsel_quant_kernel<<<nchunks, 256, 0, stream>>>((const fx4*)x, ws_a, ws_s,
                                                     (fx4*)(out + 2 * B),
                                                     per_b4, chunk4, nchunks);
}